// Round 4
// baseline (282.835 us; speedup 1.0000x reference)
//
#include <hip/hip_runtime.h>

// LSTM: B=2048, T=512, INPUT=2, H=32, OUT=1. One wave per batch element.
// Lane j (0..63) owns gate rows j and j+64:
//   lanes 0..31  -> i_j, g_j ; lanes 32..63 -> f_{j-32}, o_{j-32}
// Round 8 = Round 7 with the LDS h-broadcast replaced by v_readlane -> SGPR:
//  - every lane's hnew holds h_{lane&31}; 32 readlanes (const lane idx) give
//    the whole h-vector as wave-uniform scalars. v_pk_fma_f32 consumes them
//    as 64-bit SGPR-pair operands. Removes 8 ds_read_b128/step AND takes the
//    ds_write->ds_read LDS round-trip (~100+ cy) out of the recurrence chain;
//    the chain is now pure VALU. +23 issue ops/step, paid from the ~31%
//    stall observed in R7 (VALUBusy 69%).
//  - the combined per-step write remains (high lanes: FC history; low lanes:
//    dead broadcast slot kept as sink to avoid divergence) but is now fully
//    off-chain (only read at chunk flush).
// Carried from R7:
//  - __builtin_amdgcn_exp2f (bare v_exp_f32), no libm fixup.
//  - store pointer as induction variable (wr += winc).
//  - v_permlane32_swap_b32 gate exchange; pair = {vdst_new, vsrc_new}.
//  - log2e folded into weights/biases; c kept in 2*log2e scale;
//    h = fma(2*ov, sigm(c'), -ov).
//  - x read as one b128 per 2 timesteps from LDS staging.

#define BB 2048
#define TT 512
#define HH 32
#define CHUNK 64
#define HROW 33   // FC-history row stride: (lane+u)%32 -> 2-way alias = free

#define LOG2E 1.44269504088896340736f

typedef float v2f __attribute__((ext_vector_type(2)));
typedef float v4f __attribute__((ext_vector_type(4)));
typedef unsigned int v2u __attribute__((ext_vector_type(2)));

__device__ __forceinline__ float sigm2(float xs) {
    // xs is log2e-scaled: returns 1/(1+2^-xs) = sigmoid(xs/log2e)
    return __builtin_amdgcn_rcpf(1.0f + __builtin_amdgcn_exp2f(-xs));
}

__global__ __launch_bounds__(256, 2) void lstm_fused_kernel(
    const float* __restrict__ x,     // [B, T, 2]
    const float* __restrict__ W_ih,  // [128, 2]
    const float* __restrict__ W_hh,  // [128, 32]
    const float* __restrict__ b_ih,  // [128]
    const float* __restrict__ b_hh,  // [128]
    const float* __restrict__ W_fc,  // [1, 32]
    const float* __restrict__ b_fc,  // [1]
    float* __restrict__ out)         // [B, T, 1]
{
    __shared__ float lds_x[4 * TT * 2];              // 16 KB  x staging
    __shared__ float lds_h[4 * CHUNK * HROW];        // 33 KB  FC history
    __shared__ __align__(16) float lds_bc[4][64];    // 1 KB   write sink

    const int lane = threadIdx.x & 63;
    const int wv   = threadIdx.x >> 6;
    const int b    = blockIdx.x * 4 + wv;
    const bool low = (lane < 32);

    // ---- stage x[T,2] into LDS, coalesced float4 (wave-private, no barrier) ----
    {
        const float4* xg = (const float4*)(x + (size_t)b * TT * 2);
        float4* xs = (float4*)(lds_x + wv * TT * 2);
        #pragma unroll
        for (int r = 0; r < 4; ++r) xs[r * 64 + lane] = xg[r * 64 + lane];
    }

    // ---- per-lane weights, packed in k-pairs, PRE-SCALED by log2e ----
    // rows rlo (i/f): scale log2e  -> sigmoid = rcp(1+exp2(-g'))
    // rows rhi: low lanes (g): scale 2*log2e (tanh(x)=2*sigm(2x)-1)
    //           high lanes (o): scale log2e
    const int rlo = lane;
    const int rhi = lane + 64;
    const float sl = LOG2E;
    const float sh = low ? 2.0f * LOG2E : LOG2E;

    const v2f wihl = ((const v2f*)W_ih)[rlo] * sl;
    const v2f wihh = ((const v2f*)W_ih)[rhi] * sh;
    const float bl = (b_ih[rlo] + b_hh[rlo]) * sl;
    const float bh = (b_ih[rhi] + b_hh[rhi]) * sh;

    v2f wloq[HH / 2], whiq[HH / 2];
    #pragma unroll
    for (int k = 0; k < HH / 2; ++k) {
        wloq[k] = ((const v2f*)(W_hh + rlo * HH))[k] * sl;
        whiq[k] = ((const v2f*)(W_hh + rhi * HH))[k] * sh;
    }

    // FC weights (wave-uniform -> SGPRs)
    float wfc[HH];
    #pragma unroll
    for (int u = 0; u < HH; ++u) wfc[u] = W_fc[u];
    const float bfc = b_fc[0];

    // hi-gate activation: low lanes produce g' = 2*log2e*tanh(g) directly:
    //   g' = 4*log2e*sigm(2g) - 2*log2e ; high lanes: plain sigmoid(o)
    const float Aa = low ?  4.0f * LOG2E : 1.0f;
    const float Bb = low ? -2.0f * LOG2E : 0.0f;

    float c = 0.0f;   // c' = 2*log2e * c_true

    float* out_b = out + (size_t)b * TT;
    const v4f* xw4 = (const v4f*)(lds_x + wv * TT * 2);
    float* hb  = lds_h + wv * CHUNK * HROW;
    float* bcw = lds_bc[wv];

    const v2f binitL = {bl, 0.0f};
    const v2f binitH = {bh, 0.0f};

    // h state as wave-uniform scalars (expect SGPRs after readlane)
    float hs[HH];
    #pragma unroll
    for (int k = 0; k < HH; ++k) hs[k] = 0.0f;   // h_{-1} = 0

    // per-lane store pointer as induction variable:
    // low lanes: dead sink slot; high lanes: walk FC-history rows
    float* wr = low ? (bcw + lane) : (hb + (lane - 32));
    const int winc = low ? 0 : HROW;

    #pragma unroll 1
    for (int ch = 0; ch < TT / CHUNK; ++ch) {
        #pragma unroll 1
        for (int uu = 0; uu < CHUNK; uu += 2) {
            // one b128 covers x_t and x_{t+1}
            v4f xq = xw4[(ch * CHUNK + uu) >> 1];

            #pragma unroll
            for (int s = 0; s < 2; ++s) {
                v2f xt = s ? (v2f){xq.z, xq.w} : (v2f){xq.x, xq.y};

                // x-projection + bias (pre-scaled), packed
                v2f aL0 = __builtin_elementwise_fma(xt, wihl, binitL);
                v2f aH0 = __builtin_elementwise_fma(xt, wihh, binitH);
                v2f aL1 = {0.0f, 0.0f};
                v2f aH1 = {0.0f, 0.0f};

                // recurrent dot: 4 chains of 8 pk-FMAs, h from uniform scalars
                #pragma unroll
                for (int k = 0; k < HH / 2; ++k) {
                    v2f hp = {hs[2 * k], hs[2 * k + 1]};
                    if (k < HH / 4) {
                        aL0 = __builtin_elementwise_fma(hp, wloq[k], aL0);
                        aH0 = __builtin_elementwise_fma(hp, whiq[k], aH0);
                    } else {
                        aL1 = __builtin_elementwise_fma(hp, wloq[k], aL1);
                        aH1 = __builtin_elementwise_fma(hp, whiq[k], aH1);
                    }
                }
                v2f aL = aL0 + aL1;
                v2f aH = aH0 + aH1;
                float glo = aL.x + aL.y;   // log2e-scaled pre-activation
                float ghi = aH.x + aH.y;   // (scaled) pre-activation

                // sigmoid via bare v_exp_f32 (neg = free input modifier)
                float alo = sigm2(glo);                 // i / f
                float shi = sigm2(ghi);
                float ahi = fmaf(Aa, shi, Bb);          // g' / o

                // half-wave exchange via v_permlane32_swap_b32.
                // pair = {vdst_new, vsrc_new}:
                //   .y = (low: cross, high: own)   .x = (low: own, high: cross)
                v2u r1 = __builtin_amdgcn_permlane32_swap(
                    __float_as_uint(alo), __float_as_uint(alo), false, false);
                v2u r2 = __builtin_amdgcn_permlane32_swap(
                    __float_as_uint(ahi), __float_as_uint(ahi), false, false);
                float fv = __uint_as_float(r1.y);   // sigm(f)
                float iv = __uint_as_float(r1.x);   // sigm(i)
                float ov = __uint_as_float(r2.y);   // sigm(o)
                float gv = __uint_as_float(r2.x);   // 2*log2e*tanh(g)

                // c' = f*c' + i*g'   (stays in 2*log2e scale)
                float ig = iv * gv;
                c = fmaf(fv, c, ig);

                // h = o * tanh(c) = fma(2*o, sigm(c'), -o); 2*o off critical path
                float rr  = sigm2(c);
                float ov2 = ov + ov;
                float hnew = fmaf(ov2, rr, -ov);    // valid on ALL lanes

                // FC-history write (high lanes); low lanes hit dead sink.
                // Off the recurrence chain entirely.
                *wr = hnew;
                wr += winc;

                // broadcast h via readlane -> wave-uniform scalars (SGPRs);
                // lane k (low half) holds h_k. Pure-VALU chain, no LDS.
                #pragma unroll
                for (int k = 0; k < HH; ++k)
                    hs[k] = __uint_as_float(
                        __builtin_amdgcn_readlane(__float_as_uint(hnew), k));
            }
        }

        // rewind high-lane history pointer for next chunk (low: no-op)
        wr -= winc * CHUNK;

        // ---- chunk flush: FC for 64 timesteps, coalesced store ----
        float acc = bfc;
        const float* row = hb + lane * HROW;
        #pragma unroll
        for (int u = 0; u < HH; ++u)
            acc = fmaf(row[u], wfc[u], acc);
        out_b[ch * CHUNK + lane] = acc;
    }
}

extern "C" void kernel_launch(void* const* d_in, const int* in_sizes, int n_in,
                              void* d_out, int out_size, void* d_ws, size_t ws_size,
                              hipStream_t stream) {
    const float* x    = (const float*)d_in[0];
    const float* W_ih = (const float*)d_in[1];
    const float* W_hh = (const float*)d_in[2];
    const float* b_ih = (const float*)d_in[3];
    const float* b_hh = (const float*)d_in[4];
    const float* W_fc = (const float*)d_in[5];
    const float* b_fc = (const float*)d_in[6];
    float* out = (float*)d_out;

    dim3 grid(BB / 4);
    dim3 block(256);
    lstm_fused_kernel<<<grid, block, 0, stream>>>(x, W_ih, W_hh, b_ih, b_hh,
                                                  W_fc, b_fc, out);
}

// Round 5
// 225.364 us; speedup vs baseline: 1.2550x; 1.2550x over previous
//
#include <hip/hip_runtime.h>

// LSTM: B=2048, T=512, INPUT=2, H=32, OUT=1. One wave per batch element.
// Lane j (0..63) owns gate rows j and j+64:
//   lanes 0..31  -> i_j, g_j ; lanes 32..63 -> f_{j-32}, o_{j-32}
// Round 9 = Round 7 (revert of R8's readlane experiment: readlane broadcast
// cost +70% VALU busy-time; LDS broadcast does 32 values in 9 ops) plus:
//  - recurrent dot / x-proj / reduction forced to packed VOP3P via inline asm
//    (v_pk_fma_f32 / v_pk_add_f32). Theory: measured VALU-busy (~260
//    cy/wave/step) is ~2x the hand count assuming packed ops; suspect
//    __builtin_elementwise_fma(v2f) scalarizes to 2x v_fma_f32.
//  - 4-way accumulator split per gate path: FMA chain depth 8 -> 5.
// Carried from R7:
//  - h broadcast via LDS (write hnew, read 8x b128 same-address next step).
//  - __builtin_amdgcn_exp2f (bare v_exp_f32), no libm fixup.
//  - store pointer as induction variable (wr += winc).
//  - v_permlane32_swap_b32 gate exchange; pair = {vdst_new, vsrc_new}.
//  - log2e folded into weights/biases; c kept in 2*log2e scale;
//    h = fma(2*ov, sigm(c'), -ov).
//  - x read as one b128 per 2 timesteps from LDS staging.

#define BB 2048
#define TT 512
#define HH 32
#define CHUNK 64
#define HROW 33   // FC-history row stride: (lane+u)%32 -> 2-way alias = free

#define LOG2E 1.44269504088896340736f

typedef float v2f __attribute__((ext_vector_type(2)));
typedef float v4f __attribute__((ext_vector_type(4)));
typedef unsigned int v2u __attribute__((ext_vector_type(2)));

__device__ __forceinline__ float sigm2(float xs) {
    // xs is log2e-scaled: returns 1/(1+2^-xs) = sigmoid(xs/log2e)
    return __builtin_amdgcn_rcpf(1.0f + __builtin_amdgcn_exp2f(-xs));
}

// forced packed fp32 FMA: d = a*b + c (VOP3P, default op_sel_hi = packed)
__device__ __forceinline__ v2f pk_fma(v2f a, v2f b, v2f c) {
    v2f d;
    asm("v_pk_fma_f32 %0, %1, %2, %3" : "=v"(d) : "v"(a), "v"(b), "v"(c));
    return d;
}
__device__ __forceinline__ v2f pk_add(v2f a, v2f b) {
    v2f d;
    asm("v_pk_add_f32 %0, %1, %2" : "=v"(d) : "v"(a), "v"(b));
    return d;
}

__global__ __launch_bounds__(256, 2) void lstm_fused_kernel(
    const float* __restrict__ x,     // [B, T, 2]
    const float* __restrict__ W_ih,  // [128, 2]
    const float* __restrict__ W_hh,  // [128, 32]
    const float* __restrict__ b_ih,  // [128]
    const float* __restrict__ b_hh,  // [128]
    const float* __restrict__ W_fc,  // [1, 32]
    const float* __restrict__ b_fc,  // [1]
    float* __restrict__ out)         // [B, T, 1]
{
    __shared__ float lds_x[4 * TT * 2];              // 16 KB  x staging
    __shared__ float lds_h[4 * CHUNK * HROW];        // 33 KB  FC history
    __shared__ __align__(16) float lds_bc[4][64];    // 1 KB   h broadcast

    const int lane = threadIdx.x & 63;
    const int wv   = threadIdx.x >> 6;
    const int b    = blockIdx.x * 4 + wv;
    const bool low = (lane < 32);

    // ---- stage x[T,2] into LDS, coalesced float4 (wave-private, no barrier) ----
    {
        const float4* xg = (const float4*)(x + (size_t)b * TT * 2);
        float4* xs = (float4*)(lds_x + wv * TT * 2);
        #pragma unroll
        for (int r = 0; r < 4; ++r) xs[r * 64 + lane] = xg[r * 64 + lane];
    }

    // ---- per-lane weights, packed in k-pairs, PRE-SCALED by log2e ----
    // rows rlo (i/f): scale log2e  -> sigmoid = rcp(1+exp2(-g'))
    // rows rhi: low lanes (g): scale 2*log2e (tanh(x)=2*sigm(2x)-1)
    //           high lanes (o): scale log2e
    const int rlo = lane;
    const int rhi = lane + 64;
    const float sl = LOG2E;
    const float sh = low ? 2.0f * LOG2E : LOG2E;

    const v2f wihl = ((const v2f*)W_ih)[rlo] * sl;
    const v2f wihh = ((const v2f*)W_ih)[rhi] * sh;
    const float bl = (b_ih[rlo] + b_hh[rlo]) * sl;
    const float bh = (b_ih[rhi] + b_hh[rhi]) * sh;

    v2f wloq[HH / 2], whiq[HH / 2];
    #pragma unroll
    for (int k = 0; k < HH / 2; ++k) {
        wloq[k] = ((const v2f*)(W_hh + rlo * HH))[k] * sl;
        whiq[k] = ((const v2f*)(W_hh + rhi * HH))[k] * sh;
    }

    // FC weights (wave-uniform -> SGPRs)
    float wfc[HH];
    #pragma unroll
    for (int u = 0; u < HH; ++u) wfc[u] = W_fc[u];
    const float bfc = b_fc[0];

    // hi-gate activation: low lanes produce g' = 2*log2e*tanh(g) directly:
    //   g' = 4*log2e*sigm(2g) - 2*log2e ; high lanes: plain sigmoid(o)
    const float Aa = low ?  4.0f * LOG2E : 1.0f;
    const float Bb = low ? -2.0f * LOG2E : 0.0f;

    float c = 0.0f;   // c' = 2*log2e * c_true

    float* out_b = out + (size_t)b * TT;
    const v4f* xw4 = (const v4f*)(lds_x + wv * TT * 2);
    float* hb  = lds_h + wv * CHUNK * HROW;
    float* bcw = lds_bc[wv];
    const v4f* bcr = (const v4f*)bcw;

    bcw[lane] = 0.0f;   // h_{-1} = 0 (same-wave in-order LDS)

    const v2f binitL = {bl, 0.0f};
    const v2f binitH = {bh, 0.0f};

    // per-lane store pointer as induction variable:
    // low lanes: fixed broadcast slot; high lanes: walk FC-history rows
    float* wr = low ? (bcw + lane) : (hb + (lane - 32));
    const int winc = low ? 0 : HROW;

    #pragma unroll 1
    for (int ch = 0; ch < TT / CHUNK; ++ch) {
        #pragma unroll 1
        for (int uu = 0; uu < CHUNK; uu += 2) {
            // one b128 covers x_t and x_{t+1}
            v4f xq = xw4[(ch * CHUNK + uu) >> 1];

            #pragma unroll
            for (int s = 0; s < 2; ++s) {
                // broadcast h_{t-1}: 8 quad reads, all lanes same address
                v4f hq[8];
                #pragma unroll
                for (int q = 0; q < 8; ++q) hq[q] = bcr[q];

                v2f xt = s ? (v2f){xq.z, xq.w} : (v2f){xq.x, xq.y};

                // x-projection + bias (pre-scaled), packed; these start
                // accumulator chains 0 (depth 5), chains 1-3 depth 4
                v2f aL[4], aH[4];
                aL[0] = pk_fma(xt, wihl, binitL);
                aH[0] = pk_fma(xt, wihh, binitH);
                aL[1] = (v2f){0.0f, 0.0f}; aL[2] = (v2f){0.0f, 0.0f};
                aL[3] = (v2f){0.0f, 0.0f};
                aH[1] = (v2f){0.0f, 0.0f}; aH[2] = (v2f){0.0f, 0.0f};
                aH[3] = (v2f){0.0f, 0.0f};

                // recurrent dot: 4-way round-robin accumulators, packed FMAs
                #pragma unroll
                for (int k = 0; k < HH / 2; ++k) {
                    v2f hp = (k & 1)
                        ? __builtin_shufflevector(hq[k >> 1], hq[k >> 1], 2, 3)
                        : __builtin_shufflevector(hq[k >> 1], hq[k >> 1], 0, 1);
                    aL[k & 3] = pk_fma(hp, wloq[k], aL[k & 3]);
                    aH[k & 3] = pk_fma(hp, whiq[k], aH[k & 3]);
                }
                v2f aLt = pk_add(pk_add(aL[0], aL[1]), pk_add(aL[2], aL[3]));
                v2f aHt = pk_add(pk_add(aH[0], aH[1]), pk_add(aH[2], aH[3]));
                float glo = aLt.x + aLt.y;   // log2e-scaled pre-activation
                float ghi = aHt.x + aHt.y;   // (scaled) pre-activation

                // sigmoid via bare v_exp_f32 (neg = free input modifier)
                float alo = sigm2(glo);                 // i / f
                float shi = sigm2(ghi);
                float ahi = fmaf(Aa, shi, Bb);          // g' / o

                // half-wave exchange via v_permlane32_swap_b32.
                // pair = {vdst_new, vsrc_new}:
                //   .y = (low: cross, high: own)   .x = (low: own, high: cross)
                v2u r1 = __builtin_amdgcn_permlane32_swap(
                    __float_as_uint(alo), __float_as_uint(alo), false, false);
                v2u r2 = __builtin_amdgcn_permlane32_swap(
                    __float_as_uint(ahi), __float_as_uint(ahi), false, false);
                float fv = __uint_as_float(r1.y);   // sigm(f)
                float iv = __uint_as_float(r1.x);   // sigm(i)
                float ov = __uint_as_float(r2.y);   // sigm(o)
                float gv = __uint_as_float(r2.x);   // 2*log2e*tanh(g)

                // c' = f*c' + i*g'   (stays in 2*log2e scale)
                float ig = iv * gv;
                c = fmaf(fv, c, ig);

                // h = o * tanh(c) = fma(2*o, sigm(c'), -o); 2*o off critical path
                float rr  = sigm2(c);
                float ov2 = ov + ov;
                float hnew = fmaf(ov2, rr, -ov);    // valid on ALL lanes

                // single combined write: low lanes -> broadcast slot,
                // high lanes -> FC history row u (pointer walks by HROW)
                *wr = hnew;
                wr += winc;
            }
        }

        // rewind high-lane history pointer for next chunk (low: no-op)
        wr -= winc * CHUNK;

        // ---- chunk flush: FC for 64 timesteps, coalesced store ----
        float acc = bfc;
        const float* row = hb + lane * HROW;
        #pragma unroll
        for (int u = 0; u < HH; ++u)
            acc = fmaf(row[u], wfc[u], acc);
        out_b[ch * CHUNK + lane] = acc;
    }
}

extern "C" void kernel_launch(void* const* d_in, const int* in_sizes, int n_in,
                              void* d_out, int out_size, void* d_ws, size_t ws_size,
                              hipStream_t stream) {
    const float* x    = (const float*)d_in[0];
    const float* W_ih = (const float*)d_in[1];
    const float* W_hh = (const float*)d_in[2];
    const float* b_ih = (const float*)d_in[3];
    const float* b_hh = (const float*)d_in[4];
    const float* W_fc = (const float*)d_in[5];
    const float* b_fc = (const float*)d_in[6];
    float* out = (float*)d_out;

    dim3 grid(BB / 4);
    dim3 block(256);
    lstm_fused_kernel<<<grid, block, 0, stream>>>(x, W_ih, W_hh, b_ih, b_hh,
                                                  W_fc, b_fc, out);
}

// Round 6
// 211.881 us; speedup vs baseline: 1.3349x; 1.0636x over previous
//
#include <hip/hip_runtime.h>

// LSTM: B=2048, T=512, INPUT=2, H=32, OUT=1. One wave per batch element.
// Lane j (0..63) owns gate rows j and j+64:
//   lanes 0..31  -> i_j, g_j ; lanes 32..63 -> f_{j-32}, o_{j-32}
// Round 10 = Round 7 (the empirical best, 176 us rocprof) + two codegen trims:
//  - chain-1 accumulators start with an explicit packed MUL at k=8 instead of
//    zero-init + fma (LLVM can't fold fma(a,b,+0) w/o nsz; saves 4 v_mov/step).
//  - timestep loop unrolled to 4 steps/iteration (2x b128 x-loads): halves
//    loop overhead and widens the scheduler window so off-chain work of
//    steps t+1..t+3 issues under step t's LDS round-trip stall.
// History: R8 readlane-broadcast (+70% busy, reverted), R9 inline-asm pk_fma
// (+10% busy from asm-forced v_movs -> builtin was already packed, reverted).
// Carried from R7:
//  - h broadcast via LDS (write hnew, read 8x b128 same-address next step).
//  - __builtin_amdgcn_exp2f (bare v_exp_f32), no libm fixup.
//  - store pointer as induction variable (wr += winc).
//  - v_permlane32_swap_b32 gate exchange; pair = {vdst_new, vsrc_new}.
//  - log2e folded into weights/biases; c kept in 2*log2e scale;
//    h = fma(2*ov, sigm(c'), -ov).

#define BB 2048
#define TT 512
#define HH 32
#define CHUNK 64
#define HROW 33   // FC-history row stride: (lane+u)%32 -> 2-way alias = free

#define LOG2E 1.44269504088896340736f

typedef float v2f __attribute__((ext_vector_type(2)));
typedef float v4f __attribute__((ext_vector_type(4)));
typedef unsigned int v2u __attribute__((ext_vector_type(2)));

__device__ __forceinline__ float sigm2(float xs) {
    // xs is log2e-scaled: returns 1/(1+2^-xs) = sigmoid(xs/log2e)
    return __builtin_amdgcn_rcpf(1.0f + __builtin_amdgcn_exp2f(-xs));
}

__global__ __launch_bounds__(256, 2) void lstm_fused_kernel(
    const float* __restrict__ x,     // [B, T, 2]
    const float* __restrict__ W_ih,  // [128, 2]
    const float* __restrict__ W_hh,  // [128, 32]
    const float* __restrict__ b_ih,  // [128]
    const float* __restrict__ b_hh,  // [128]
    const float* __restrict__ W_fc,  // [1, 32]
    const float* __restrict__ b_fc,  // [1]
    float* __restrict__ out)         // [B, T, 1]
{
    __shared__ float lds_x[4 * TT * 2];              // 16 KB  x staging
    __shared__ float lds_h[4 * CHUNK * HROW];        // 33 KB  FC history
    __shared__ __align__(16) float lds_bc[4][64];    // 1 KB   h broadcast

    const int lane = threadIdx.x & 63;
    const int wv   = threadIdx.x >> 6;
    const int b    = blockIdx.x * 4 + wv;
    const bool low = (lane < 32);

    // ---- stage x[T,2] into LDS, coalesced float4 (wave-private, no barrier) ----
    {
        const float4* xg = (const float4*)(x + (size_t)b * TT * 2);
        float4* xs = (float4*)(lds_x + wv * TT * 2);
        #pragma unroll
        for (int r = 0; r < 4; ++r) xs[r * 64 + lane] = xg[r * 64 + lane];
    }

    // ---- per-lane weights, packed in k-pairs, PRE-SCALED by log2e ----
    // rows rlo (i/f): scale log2e  -> sigmoid = rcp(1+exp2(-g'))
    // rows rhi: low lanes (g): scale 2*log2e (tanh(x)=2*sigm(2x)-1)
    //           high lanes (o): scale log2e
    const int rlo = lane;
    const int rhi = lane + 64;
    const float sl = LOG2E;
    const float sh = low ? 2.0f * LOG2E : LOG2E;

    const v2f wihl = ((const v2f*)W_ih)[rlo] * sl;
    const v2f wihh = ((const v2f*)W_ih)[rhi] * sh;
    const float bl = (b_ih[rlo] + b_hh[rlo]) * sl;
    const float bh = (b_ih[rhi] + b_hh[rhi]) * sh;

    v2f wloq[HH / 2], whiq[HH / 2];
    #pragma unroll
    for (int k = 0; k < HH / 2; ++k) {
        wloq[k] = ((const v2f*)(W_hh + rlo * HH))[k] * sl;
        whiq[k] = ((const v2f*)(W_hh + rhi * HH))[k] * sh;
    }

    // FC weights (wave-uniform -> SGPRs)
    float wfc[HH];
    #pragma unroll
    for (int u = 0; u < HH; ++u) wfc[u] = W_fc[u];
    const float bfc = b_fc[0];

    // hi-gate activation: low lanes produce g' = 2*log2e*tanh(g) directly:
    //   g' = 4*log2e*sigm(2g) - 2*log2e ; high lanes: plain sigmoid(o)
    const float Aa = low ?  4.0f * LOG2E : 1.0f;
    const float Bb = low ? -2.0f * LOG2E : 0.0f;

    float c = 0.0f;   // c' = 2*log2e * c_true

    float* out_b = out + (size_t)b * TT;
    const v4f* xw4 = (const v4f*)(lds_x + wv * TT * 2);
    float* hb  = lds_h + wv * CHUNK * HROW;
    float* bcw = lds_bc[wv];
    const v4f* bcr = (const v4f*)bcw;

    bcw[lane] = 0.0f;   // h_{-1} = 0 (same-wave in-order LDS)

    const v2f binitL = {bl, 0.0f};
    const v2f binitH = {bh, 0.0f};

    // per-lane store pointer as induction variable:
    // low lanes: fixed broadcast slot; high lanes: walk FC-history rows
    float* wr = low ? (bcw + lane) : (hb + (lane - 32));
    const int winc = low ? 0 : HROW;

    #pragma unroll 1
    for (int ch = 0; ch < TT / CHUNK; ++ch) {
        #pragma unroll 1
        for (int uu = 0; uu < CHUNK; uu += 4) {
            // two b128 cover x_t .. x_{t+3}
            v4f xq0 = xw4[(ch * CHUNK + uu) >> 1];
            v4f xq1 = xw4[((ch * CHUNK + uu) >> 1) + 1];

            #pragma unroll
            for (int s = 0; s < 4; ++s) {
                // broadcast h_{t-1}: 8 quad reads, all lanes same address
                v4f hq[8];
                #pragma unroll
                for (int q = 0; q < 8; ++q) hq[q] = bcr[q];

                v2f xt;
                if      (s == 0) xt = (v2f){xq0.x, xq0.y};
                else if (s == 1) xt = (v2f){xq0.z, xq0.w};
                else if (s == 2) xt = (v2f){xq1.x, xq1.y};
                else             xt = (v2f){xq1.z, xq1.w};

                // x-projection + bias (pre-scaled), packed; starts chain 0
                v2f aL0 = __builtin_elementwise_fma(xt, wihl, binitL);
                v2f aH0 = __builtin_elementwise_fma(xt, wihh, binitH);
                v2f aL1, aH1;

                // recurrent dot: 2 chains of 8-9 packed FMAs; chain 1 starts
                // with an explicit packed MUL (no zero-init movs)
                #pragma unroll
                for (int k = 0; k < HH / 2; ++k) {
                    v2f hp = (k & 1)
                        ? __builtin_shufflevector(hq[k >> 1], hq[k >> 1], 2, 3)
                        : __builtin_shufflevector(hq[k >> 1], hq[k >> 1], 0, 1);
                    if (k < HH / 4) {
                        aL0 = __builtin_elementwise_fma(hp, wloq[k], aL0);
                        aH0 = __builtin_elementwise_fma(hp, whiq[k], aH0);
                    } else if (k == HH / 4) {
                        aL1 = hp * wloq[k];
                        aH1 = hp * whiq[k];
                    } else {
                        aL1 = __builtin_elementwise_fma(hp, wloq[k], aL1);
                        aH1 = __builtin_elementwise_fma(hp, whiq[k], aH1);
                    }
                }
                v2f aL = aL0 + aL1;
                v2f aH = aH0 + aH1;
                float glo = aL.x + aL.y;   // log2e-scaled pre-activation
                float ghi = aH.x + aH.y;   // (scaled) pre-activation

                // sigmoid via bare v_exp_f32 (neg = free input modifier)
                float alo = sigm2(glo);                 // i / f
                float shi = sigm2(ghi);
                float ahi = fmaf(Aa, shi, Bb);          // g' / o

                // half-wave exchange via v_permlane32_swap_b32.
                // pair = {vdst_new, vsrc_new}:
                //   .y = (low: cross, high: own)   .x = (low: own, high: cross)
                v2u r1 = __builtin_amdgcn_permlane32_swap(
                    __float_as_uint(alo), __float_as_uint(alo), false, false);
                v2u r2 = __builtin_amdgcn_permlane32_swap(
                    __float_as_uint(ahi), __float_as_uint(ahi), false, false);
                float fv = __uint_as_float(r1.y);   // sigm(f)
                float iv = __uint_as_float(r1.x);   // sigm(i)
                float ov = __uint_as_float(r2.y);   // sigm(o)
                float gv = __uint_as_float(r2.x);   // 2*log2e*tanh(g)

                // c' = f*c' + i*g'   (stays in 2*log2e scale)
                float ig = iv * gv;
                c = fmaf(fv, c, ig);

                // h = o * tanh(c) = fma(2*o, sigm(c'), -o); 2*o off critical path
                float rr  = sigm2(c);
                float ov2 = ov + ov;
                float hnew = fmaf(ov2, rr, -ov);    // valid on ALL lanes

                // single combined write: low lanes -> broadcast slot,
                // high lanes -> FC history row u (pointer walks by HROW)
                *wr = hnew;
                wr += winc;
            }
        }

        // rewind high-lane history pointer for next chunk (low: no-op)
        wr -= winc * CHUNK;

        // ---- chunk flush: FC for 64 timesteps, coalesced store ----
        float acc = bfc;
        const float* row = hb + lane * HROW;
        #pragma unroll
        for (int u = 0; u < HH; ++u)
            acc = fmaf(row[u], wfc[u], acc);
        out_b[ch * CHUNK + lane] = acc;
    }
}

extern "C" void kernel_launch(void* const* d_in, const int* in_sizes, int n_in,
                              void* d_out, int out_size, void* d_ws, size_t ws_size,
                              hipStream_t stream) {
    const float* x    = (const float*)d_in[0];
    const float* W_ih = (const float*)d_in[1];
    const float* W_hh = (const float*)d_in[2];
    const float* b_ih = (const float*)d_in[3];
    const float* b_hh = (const float*)d_in[4];
    const float* W_fc = (const float*)d_in[5];
    const float* b_fc = (const float*)d_in[6];
    float* out = (float*)d_out;

    dim3 grid(BB / 4);
    dim3 block(256);
    lstm_fused_kernel<<<grid, block, 0, stream>>>(x, W_ih, W_hh, b_ih, b_hh,
                                                  W_fc, b_fc, out);
}

// Round 7
// 205.473 us; speedup vs baseline: 1.3765x; 1.0312x over previous
//
#include <hip/hip_runtime.h>

// LSTM: B=2048, T=512, INPUT=2, H=32, OUT=1.
// Round 11: TWO batch elements per wave, fully lane-local gates.
//   lanes 0..31 -> element A, lanes 32..63 -> element B
//   lane owns ALL FOUR gate rows (i_j, f_j, g_j, o_j) of unit j = lane&31.
// Why: R4-R10 established wall/step ~811 cy/SIMD = ~576 busy (2 waves) +
// exposed serial chain (LDS h round-trip + 2 sigm chains). This structure:
//  - eliminates the cross-lane gate exchange entirely (c-update lane-local:
//    no permlane, no copies, no divergent selects),
//  - shares ONE LDS round-trip per step between 2 elements (1 ds_write_b32 +
//    8 ds_read_b128 broadcast with 2 unique addrs -> 2-way = free),
//  - halves per-element issue (~98 VALU/step for 2 elems vs ~144/elem).
// Cost: 1024 waves -> 1 wave/SIMD; per model the 2nd wave was hiding inside
// the shared chain anyway.
// History rows (ROWF=36, 16B-aligned) double as broadcast source: rd = wr-j.
// Per-gate arithmetic bit-identical to R10 (same chain split: chain0 =
// xproj + k0..7, chain1 = mul@k8 + fma k9..15; same activation forms;
// scalar FC flush) -> absmax should match 0.001953125 exactly.
// Carried: log2e pre-scaled weights, bare v_exp_f32 sigm, c in 2*log2e scale,
// h = fma(2*o, sigm(c'), -o), x prefetched one 4-step iteration ahead.

#define BB 2048
#define TT 512
#define HH 32
#define CHUNK 32
#define ROWF 36                            // floats per history row (16B-aligned)
#define EPAD 4                             // elem-B base pad: bank shift, keeps 16B align
#define WSTRIDE (2 * CHUNK * ROWF + EPAD)  // 2308 floats per wave

#define LOG2E 1.44269504088896340736f

typedef float v2f __attribute__((ext_vector_type(2)));
typedef float v4f __attribute__((ext_vector_type(4)));

__device__ __forceinline__ float sigm2(float xs) {
    // xs is log2e-scaled: returns 1/(1+2^-xs) = sigmoid(xs/log2e)
    return __builtin_amdgcn_rcpf(1.0f + __builtin_amdgcn_exp2f(-xs));
}

__global__ __launch_bounds__(256, 1) void lstm_fused_kernel(
    const float* __restrict__ x,     // [B, T, 2]
    const float* __restrict__ W_ih,  // [128, 2]
    const float* __restrict__ W_hh,  // [128, 32]
    const float* __restrict__ b_ih,  // [128]
    const float* __restrict__ b_hh,  // [128]
    const float* __restrict__ W_fc,  // [1, 32]
    const float* __restrict__ b_fc,  // [1]
    float* __restrict__ out)         // [B, T, 1]
{
    __shared__ __align__(16) float lds_h[4][WSTRIDE];   // 36.9 KB history

    const int lane = threadIdx.x & 63;
    const int wv   = threadIdx.x >> 6;
    const int elem = lane >> 5;          // 0 = element A, 1 = element B
    const int j    = lane & 31;          // hidden unit index
    const int b    = blockIdx.x * 8 + wv * 2 + elem;

    // gate rows for unit j (PyTorch order: i, f, g, o)
    const int ri = j, rf = HH + j, rg = 2 * HH + j, ro = 3 * HH + j;
    const float si = LOG2E;              // i, f, o scale
    const float sg = 2.0f * LOG2E;       // g scale (tanh doubling folded in)

    const v2f wihI = ((const v2f*)W_ih)[ri] * si;
    const v2f wihF = ((const v2f*)W_ih)[rf] * si;
    const v2f wihG = ((const v2f*)W_ih)[rg] * sg;
    const v2f wihO = ((const v2f*)W_ih)[ro] * si;
    const float bI = (b_ih[ri] + b_hh[ri]) * si;
    const float bF = (b_ih[rf] + b_hh[rf]) * si;
    const float bG = (b_ih[rg] + b_hh[rg]) * sg;
    const float bO = (b_ih[ro] + b_hh[ro]) * si;

    v2f wI[HH / 2], wF[HH / 2], wG[HH / 2], wO[HH / 2];
    #pragma unroll
    for (int k = 0; k < HH / 2; ++k) {
        wI[k] = ((const v2f*)(W_hh + ri * HH))[k] * si;
        wF[k] = ((const v2f*)(W_hh + rf * HH))[k] * si;
        wG[k] = ((const v2f*)(W_hh + rg * HH))[k] * sg;
        wO[k] = ((const v2f*)(W_hh + ro * HH))[k] * si;
    }

    // FC weights (wave-uniform -> expect SGPRs)
    float wfc[HH];
    #pragma unroll
    for (int u = 0; u < HH; ++u) wfc[u] = W_fc[u];
    const float bfc = b_fc[0];

    float c = 0.0f;   // c' = 2*log2e * c_true

    float* hb = &lds_h[wv][elem * (CHUNK * ROWF + EPAD)];
    float* wr = hb + j;                         // write ptr: row 0, col j
    const float* rd = hb + (CHUNK - 1) * ROWF;  // bc read: row 31 (h_{-1})

    wr[(CHUNK - 1) * ROWF] = 0.0f;              // zero h_{-1} row

    const float* xb = x + (size_t)b * (TT * 2);
    float* outp = out + (size_t)b * TT + j;

    // x prefetch: 4 timesteps = 8 floats = 2 x b128 (2 unique addrs/wave)
    v4f xq0 = *(const v4f*)(xb);
    v4f xq1 = *(const v4f*)(xb + 4);

    const v2f bI2 = {bI, 0.0f}, bF2 = {bF, 0.0f};
    const v2f bG2 = {bG, 0.0f}, bO2 = {bO, 0.0f};

    #pragma unroll 1
    for (int ch = 0; ch < TT / CHUNK; ++ch) {
        #pragma unroll 1
        for (int uu = 0; uu < CHUNK; uu += 4) {
            const int t = ch * CHUNK + uu;
            // prefetch NEXT iteration's x (clamped dummy reload at the end)
            const float* xnx = (t + 4 < TT) ? (xb + (t + 4) * 2) : xb;
            v4f nxq0 = *(const v4f*)(xnx);
            v4f nxq1 = *(const v4f*)(xnx + 4);

            #pragma unroll
            for (int s = 0; s < 4; ++s) {
                // broadcast h_{t-1}: 8 x b128, one unique addr per half-wave
                v4f hq[8];
                const v4f* rq = (const v4f*)rd;
                #pragma unroll
                for (int q = 0; q < 8; ++q) hq[q] = rq[q];

                v2f xt;
                if      (s == 0) xt = (v2f){xq0.x, xq0.y};
                else if (s == 1) xt = (v2f){xq0.z, xq0.w};
                else if (s == 2) xt = (v2f){xq1.x, xq1.y};
                else             xt = (v2f){xq1.z, xq1.w};

                // x-projection + bias starts chain 0 of each gate
                v2f aI0 = __builtin_elementwise_fma(xt, wihI, bI2);
                v2f aF0 = __builtin_elementwise_fma(xt, wihF, bF2);
                v2f aG0 = __builtin_elementwise_fma(xt, wihG, bG2);
                v2f aO0 = __builtin_elementwise_fma(xt, wihO, bO2);
                v2f aI1, aF1, aG1, aO1;

                // 4 gate dots: 2 chains each; chain 1 starts with packed MUL
                #pragma unroll
                for (int k = 0; k < HH / 2; ++k) {
                    v2f hp = (k & 1)
                        ? __builtin_shufflevector(hq[k >> 1], hq[k >> 1], 2, 3)
                        : __builtin_shufflevector(hq[k >> 1], hq[k >> 1], 0, 1);
                    if (k < HH / 4) {
                        aI0 = __builtin_elementwise_fma(hp, wI[k], aI0);
                        aF0 = __builtin_elementwise_fma(hp, wF[k], aF0);
                        aG0 = __builtin_elementwise_fma(hp, wG[k], aG0);
                        aO0 = __builtin_elementwise_fma(hp, wO[k], aO0);
                    } else if (k == HH / 4) {
                        aI1 = hp * wI[k]; aF1 = hp * wF[k];
                        aG1 = hp * wG[k]; aO1 = hp * wO[k];
                    } else {
                        aI1 = __builtin_elementwise_fma(hp, wI[k], aI1);
                        aF1 = __builtin_elementwise_fma(hp, wF[k], aF1);
                        aG1 = __builtin_elementwise_fma(hp, wG[k], aG1);
                        aO1 = __builtin_elementwise_fma(hp, wO[k], aO1);
                    }
                }
                v2f aI = aI0 + aI1, aF = aF0 + aF1;
                v2f aG = aG0 + aG1, aO = aO0 + aO1;
                float gi = aI.x + aI.y;
                float gf = aF.x + aF.y;
                float gg = aG.x + aG.y;
                float go = aO.x + aO.y;

                // activations: all lane-local, no exchange
                float iv = sigm2(gi);
                float fv = sigm2(gf);
                float ov = sigm2(go);
                float gv = fmaf(4.0f * LOG2E, sigm2(gg), -2.0f * LOG2E);

                // c' = f*c' + i*g'   (2*log2e scale)
                c = fmaf(fv, c, iv * gv);

                // h = o*tanh(c) = fma(2*o, sigm(c'), -o)
                float rr   = sigm2(c);
                float ov2  = ov + ov;
                float hnew = fmaf(ov2, rr, -ov);

                // write h into history row u; that row IS next step's
                // broadcast source (rd = row base just written)
                *wr = hnew;
                rd = wr - j;
                wr += ROWF;
            }
            xq0 = nxq0; xq1 = nxq1;
        }

        // rewind write ptr to row 0; rd stays at row 31 (carries h across
        // the chunk boundary naturally)
        wr -= CHUNK * ROWF;

        // ---- FC flush: lane handles timestep t' = j of its element ----
        float acc = bfc;
        const float* row = hb + j * ROWF;
        #pragma unroll
        for (int u = 0; u < HH; ++u)
            acc = fmaf(row[u], wfc[u], acc);
        *outp = acc;           // out[b][ch*CHUNK + j], coalesced per half
        outp += CHUNK;
    }
}

extern "C" void kernel_launch(void* const* d_in, const int* in_sizes, int n_in,
                              void* d_out, int out_size, void* d_ws, size_t ws_size,
                              hipStream_t stream) {
    const float* x    = (const float*)d_in[0];
    const float* W_ih = (const float*)d_in[1];
    const float* W_hh = (const float*)d_in[2];
    const float* b_ih = (const float*)d_in[3];
    const float* b_hh = (const float*)d_in[4];
    const float* W_fc = (const float*)d_in[5];
    const float* b_fc = (const float*)d_in[6];
    float* out = (float*)d_out;

    dim3 grid(BB / 8);    // 256 blocks x 4 waves x 2 elements = 2048
    dim3 block(256);
    lstm_fused_kernel<<<grid, block, 0, stream>>>(x, W_ih, W_hh, b_ih, b_hh,
                                                  W_fc, b_fc, out);
}